// Round 4
// baseline (224.369 us; speedup 1.0000x reference)
//
#include <hip/hip_runtime.h>
#include <stdint.h>

// BlockAttention fused: B=8, S=8192, D=H=128, BLOCK=256, WINDOW=256 (halo 255)
// No softmax => out_blk = Q_blk @ (scale * K_win^T V_win).
// ONE kernel, grid = 256 blocks (b,n) x 512 threads (8 waves), 1 block/CU.
// Per 64-key chunk: waves 0-3 project k, waves 4-7 project v (W frags in regs),
// C-tiles written TRANSPOSED into LDS [d][s] (k edge-masked), then all 8 waves
// accumulate M^T[h][d] in registers. Double-buffered chunks, 1 barrier/chunk,
// next chunk's x loads issued before this chunk's MFMAs.
// Final: q-proj -> LDS row-major, O = Q*M via LDS M^T, patch-staged f32 stores.

#define B_ 8
#define S_ 8192
#define LDC 72     // chunk tile leading dim (shorts)
#define LDM 136    // M^T LDS leading dim (shorts)
#define LDQ 136    // q tile LDS leading dim (shorts)
#define BUFB 36864 // bytes per chunk double-buffer half (kt + vt)

using bf16x8 = __attribute__((ext_vector_type(8))) short;
using f32x16 = __attribute__((ext_vector_type(16))) float;

__device__ __forceinline__ short f2bf(float f) {
  union { float f; uint32_t u; } v; v.f = f;
  uint32_t r = v.u + 0x7fffu + ((v.u >> 16) & 1u);   // RNE
  return (short)(r >> 16);
}

__device__ __forceinline__ bf16x8 cvt8(float4 a, float4 b) {
  bf16x8 r;
  r[0] = f2bf(a.x); r[1] = f2bf(a.y); r[2] = f2bf(a.z); r[3] = f2bf(a.w);
  r[4] = f2bf(b.x); r[5] = f2bf(b.y); r[6] = f2bf(b.z); r[7] = f2bf(b.w);
  return r;
}

__global__ __launch_bounds__(512) void fused_kernel(
    const float* __restrict__ x,
    const float* __restrict__ Wq, const float* __restrict__ bq,
    const float* __restrict__ Wk, const float* __restrict__ bk,
    const float* __restrict__ Wv, const float* __restrict__ bv,
    float* __restrict__ out)
{
  // [0,36864) buf0 | [36864,73728) buf1 | final: m_l=[0,34816), q_l=[36864,106496)
  __shared__ __align__(16) char smem[106496];

  const int tid  = threadIdx.x;
  const int lane = tid & 63;
  const int wv   = tid >> 6;        // 0..7
  const int c    = lane & 31;
  const int hl   = lane >> 5;

  // XCD swizzle: blk%8 = XCD -> batch b == XCD, so x[b] (4MB) fits that L2
  const int swz = (blockIdx.x & 7) * 32 + (blockIdx.x >> 3);
  const int b   = swz >> 5;
  const int n   = swz & 31;

  const int win_lo = (n == 0) ? 0 : n * 256 - 255;
  const int win_hi = (n == 31) ? S_ : n * 256 + 511;   // exclusive
  const int jlo    = (n == 0) ? 4 : 0;
  const int jhi    = (n == 31) ? 8 : 12;
  const int cbase  = n * 256 - 256;

  const float* xb = x + (size_t)b * S_ * 128;

  // ---- chunk-phase roles ----
  const bool is_k = (wv < 4);
  const int  pw   = wv & 3;
  const int  rt   = pw & 1;          // s row tile within chunk (32 rows)
  const int  ctp  = pw >> 1;         // col pair: d tiles {2ctp, 2ctp+1}
  const float* Wrole = is_k ? Wk : Wv;
  const float* brole = is_k ? bk : bv;

  // W B-frags in registers (persist through chunk loop): wfrag[t][kst]
  bf16x8 wfrag[2][8];
  float  bias2[2];
  #pragma unroll
  for (int t = 0; t < 2; ++t) {
    const int ct = 2 * ctp + t;
    bias2[t] = brole[ct * 32 + c];
    const float* wr = Wrole + (size_t)(ct * 32 + c) * 128 + hl * 8;
    #pragma unroll
    for (int kst = 0; kst < 8; ++kst) {
      float4 f0 = *(const float4*)(wr + kst * 16);
      float4 f1 = *(const float4*)(wr + kst * 16 + 4);
      wfrag[t][kst] = cvt8(f0, f1);
    }
  }

  f32x16 macc[2];
  #pragma unroll
  for (int t = 0; t < 2; ++t)
    #pragma unroll
    for (int i = 0; i < 16; ++i) macc[t][i] = 0.f;

  // prologue: load + convert x A-frags for first chunk
  bf16x8 af[8];
  {
    const float* xr = xb + (size_t)(cbase + jlo * 64 + rt * 32 + c) * 128 + hl * 8;
    #pragma unroll
    for (int kst = 0; kst < 8; ++kst) {
      float4 f0 = *(const float4*)(xr + kst * 16);
      float4 f1 = *(const float4*)(xr + kst * 16 + 4);
      af[kst] = cvt8(f0, f1);
    }
  }

  for (int j = jlo; j < jhi; ++j) {
    const int jj = j - jlo;
    short* ktc = (short*)(smem + (size_t)(jj & 1) * BUFB);
    short* vtc = ktc + 128 * LDC;
    const int c0 = cbase + j * 64;
    const bool more = (j + 1 < jhi);

    // prefetch next chunk's x rows (f32, converted after barrier)
    float4 fx[16];
    if (more) {
      const float* xr = xb + (size_t)(c0 + 64 + rt * 32 + c) * 128 + hl * 8;
      #pragma unroll
      for (int kst = 0; kst < 8; ++kst) {
        fx[2 * kst]     = *(const float4*)(xr + kst * 16);
        fx[2 * kst + 1] = *(const float4*)(xr + kst * 16 + 4);
      }
    }

    // projection MFMA: C[s_local 32][d 64] for this wave's role
    f32x16 cacc[2];
    #pragma unroll
    for (int t = 0; t < 2; ++t)
      #pragma unroll
      for (int i = 0; i < 16; ++i) cacc[t][i] = bias2[t];
    #pragma unroll
    for (int kst = 0; kst < 8; ++kst)
      #pragma unroll
      for (int t = 0; t < 2; ++t)
        cacc[t] = __builtin_amdgcn_mfma_f32_32x32x16_bf16(af[kst], wfrag[t][kst], cacc[t], 0, 0, 0);

    // transposed LDS write [d][s], k edge-masked
    short* dst = is_k ? ktc : vtc;
    const bool maskme = is_k && ((c0 < win_lo) | (c0 + 64 > win_hi));
    #pragma unroll
    for (int t = 0; t < 2; ++t) {
      const int d = (2 * ctp + t) * 32 + c;
      #pragma unroll
      for (int g = 0; g < 4; ++g) {
        #pragma unroll
        for (int p = 0; p < 2; ++p) {
          const int reg = g * 4 + p * 2;
          const int sl  = rt * 32 + g * 8 + hl * 4 + p * 2;
          float v0 = cacc[t][reg], v1 = cacc[t][reg + 1];
          if (maskme) {
            const int sg = c0 + sl;
            if (sg < win_lo || sg >= win_hi) v0 = 0.f;
            if (sg + 1 < win_lo || sg + 1 >= win_hi) v1 = 0.f;
          }
          const uint32_t pk = (uint32_t)(uint16_t)f2bf(v0) |
                              ((uint32_t)(uint16_t)f2bf(v1) << 16);
          *(uint32_t*)(dst + d * LDC + sl) = pk;
        }
      }
    }
    __syncthreads();

    // M^T accumulate: wave (ht,dh) owns 32h x 64d
    {
      const int ht = wv >> 1, dh = wv & 1;
      #pragma unroll
      for (int kst = 0; kst < 4; ++kst) {
        bf16x8 a = *(const bf16x8*)(vtc + (ht * 32 + c) * LDC + kst * 16 + hl * 8);
        #pragma unroll
        for (int ntl = 0; ntl < 2; ++ntl) {
          bf16x8 bb = *(const bf16x8*)(ktc + ((dh * 2 + ntl) * 32 + c) * LDC + kst * 16 + hl * 8);
          macc[ntl] = __builtin_amdgcn_mfma_f32_32x32x16_bf16(a, bb, macc[ntl], 0, 0, 0);
        }
      }
    }

    // convert prefetched x -> A-frags for next chunk
    if (more) {
      #pragma unroll
      for (int kst = 0; kst < 8; ++kst)
        af[kst] = cvt8(fx[2 * kst], fx[2 * kst + 1]);
    }
  }

  // ---------------- final phase ----------------
  short* m_l = (short*)smem;                 // aliases buf0 (safe: see barriers)
  short* q_l = (short*)(smem + BUFB);        // aliases buf1 + beyond

  const int rt2 = wv & 3;                    // q rows [64*rt2, +64)
  const int qcp = wv >> 2;                   // q col pair {2qcp, 2qcp+1}
  const int qs0 = n * 256;

  // issue q-phase x loads early
  float4 fxq[32];
  #pragma unroll
  for (int t = 0; t < 2; ++t) {
    const float* xr = xb + (size_t)(qs0 + rt2 * 64 + t * 32 + c) * 128 + hl * 8;
    #pragma unroll
    for (int kst = 0; kst < 8; ++kst) {
      fxq[t * 16 + 2 * kst]     = *(const float4*)(xr + kst * 16);
      fxq[t * 16 + 2 * kst + 1] = *(const float4*)(xr + kst * 16 + 4);
    }
  }

  // write scaled M^T -> m_l (buf0 region; all Mbuild readers of buf0 are done)
  const float scale = 0.08838834764831845f;  // 1/sqrt(128)
  {
    const int ht = wv >> 1, dh = wv & 1;
    #pragma unroll
    for (int ntl = 0; ntl < 2; ++ntl) {
      #pragma unroll
      for (int reg = 0; reg < 16; ++reg) {
        const int row = (reg & 3) + 8 * (reg >> 2) + 4 * hl;
        m_l[(ht * 32 + row) * LDM + (dh * 2 + ntl) * 32 + c] =
            f2bf(macc[ntl][reg] * scale);
      }
    }
  }

  // convert q-phase x (frees fxq), then issue Wq loads
  bf16x8 aq[2][8];
  #pragma unroll
  for (int t = 0; t < 2; ++t)
    #pragma unroll
    for (int kst = 0; kst < 8; ++kst)
      aq[t][kst] = cvt8(fxq[t * 16 + 2 * kst], fxq[t * 16 + 2 * kst + 1]);

  float4 fwq[32];
  float  qbias[2];
  #pragma unroll
  for (int t = 0; t < 2; ++t) {
    const int ct = 2 * qcp + t;
    qbias[t] = bq[ct * 32 + c];
    const float* wr = Wq + (size_t)(ct * 32 + c) * 128 + hl * 8;
    #pragma unroll
    for (int kst = 0; kst < 8; ++kst) {
      fwq[t * 16 + 2 * kst]     = *(const float4*)(wr + kst * 16);
      fwq[t * 16 + 2 * kst + 1] = *(const float4*)(wr + kst * 16 + 4);
    }
  }

  __syncthreads();   // B1: Mbuild(last) done (buf1) + m_l written

  bf16x8 wq[2][8];
  #pragma unroll
  for (int t = 0; t < 2; ++t)
    #pragma unroll
    for (int kst = 0; kst < 8; ++kst)
      wq[t][kst] = cvt8(fwq[t * 16 + 2 * kst], fwq[t * 16 + 2 * kst + 1]);

  // q projection: rows 64*rt2+32a, cols 32*(2qcp+t)
  f32x16 qacc[2][2];
  #pragma unroll
  for (int a = 0; a < 2; ++a)
    #pragma unroll
    for (int t = 0; t < 2; ++t)
      #pragma unroll
      for (int i = 0; i < 16; ++i) qacc[a][t][i] = qbias[t];
  #pragma unroll
  for (int kst = 0; kst < 8; ++kst)
    #pragma unroll
    for (int a = 0; a < 2; ++a)
      #pragma unroll
      for (int t = 0; t < 2; ++t)
        qacc[a][t] = __builtin_amdgcn_mfma_f32_32x32x16_bf16(aq[a][kst], wq[t][kst], qacc[a][t], 0, 0, 0);

  // q C-tiles -> q_l row-major [s_local][d]
  #pragma unroll
  for (int a = 0; a < 2; ++a) {
    #pragma unroll
    for (int t = 0; t < 2; ++t) {
      #pragma unroll
      for (int reg = 0; reg < 16; ++reg) {
        const int row = rt2 * 64 + a * 32 + (reg & 3) + 8 * (reg >> 2) + 4 * hl;
        q_l[row * LDQ + (2 * qcp + t) * 32 + c] = f2bf(qacc[a][t][reg]);
      }
    }
  }
  __syncthreads();   // B2

  // O = Q * M: wave owns q rows [32wv, +32)
  bf16x8 qf[8];
  {
    const short* qrow = q_l + (wv * 32 + c) * LDQ + hl * 8;
    #pragma unroll
    for (int kst = 0; kst < 8; ++kst) qf[kst] = *(const bf16x8*)(qrow + kst * 16);
  }
  f32x16 oacc[4];
  #pragma unroll
  for (int nt = 0; nt < 4; ++nt)
    #pragma unroll
    for (int i = 0; i < 16; ++i) oacc[nt][i] = 0.f;
  #pragma unroll
  for (int kst = 0; kst < 8; ++kst) {
    #pragma unroll
    for (int nt = 0; nt < 4; ++nt) {
      bf16x8 bb = *(const bf16x8*)(m_l + (nt * 32 + c) * LDM + kst * 16 + hl * 8);
      oacc[nt] = __builtin_amdgcn_mfma_f32_32x32x16_bf16(qf[kst], bb, oacc[nt], 0, 0, 0);
    }
  }
  __syncthreads();   // B3: all q_l reads done; patch region may be overwritten

  // epilogue: per-wave LDS patch (32x36 f32) -> coalesced float4 stores
  float* patch = (float*)(smem + BUFB) + wv * (32 * 36);
  float* outb  = out + ((size_t)b * S_ + n * 256 + wv * 32) * 128;
  #pragma unroll
  for (int nt = 0; nt < 4; ++nt) {
    #pragma unroll
    for (int reg = 0; reg < 16; ++reg) {
      const int row = (reg & 3) + 8 * (reg >> 2) + 4 * hl;
      patch[row * 36 + c] = oacc[nt][reg];
    }
    #pragma unroll
    for (int p = 0; p < 4; ++p) {
      const int row = p * 8 + (lane >> 3);
      float4 vv = *(const float4*)(patch + row * 36 + (lane & 7) * 4);
      *(float4*)(outb + (size_t)row * 128 + nt * 32 + (lane & 7) * 4) = vv;
    }
  }
}

// ---------------------------------------------------------------------------
extern "C" void kernel_launch(void* const* d_in, const int* in_sizes, int n_in,
                              void* d_out, int out_size, void* d_ws, size_t ws_size,
                              hipStream_t stream) {
  const float* x  = (const float*)d_in[0];
  const float* Wq = (const float*)d_in[1];
  const float* bq = (const float*)d_in[2];
  const float* Wk = (const float*)d_in[3];
  const float* bk = (const float*)d_in[4];
  const float* Wv = (const float*)d_in[5];
  const float* bv = (const float*)d_in[6];
  float* out = (float*)d_out;

  fused_kernel<<<256, 512, 0, stream>>>(x, Wq, bq, Wk, bk, Wv, bv, out);
}

// Round 5
// 191.323 us; speedup vs baseline: 1.1727x; 1.1727x over previous
//
#include <hip/hip_runtime.h>
#include <stdint.h>

// BlockAttention fused: B=8, S=8192, D=H=128, BLOCK=256, WINDOW=256 (halo 255)
// No softmax => out_blk = Q_blk @ (scale * K_win^T V_win).
// ONE kernel, grid = 256 blocks (b,n) x 512 threads (8 waves), 1 block/CU.
// Per 64-key chunk: waves 0-3 project k, waves 4-7 project v (W frags in regs),
// C-tiles written TRANSPOSED into LDS [d][s] (k edge-masked), then all 8 waves
// accumulate M^T[h][d] in registers. Double-buffered LDS, 1 barrier/chunk.
// Register budget: __launch_bounds__(512,2) -> 256 VGPRs; all staging buffers
// sized so peak live set stays ~224 (round-4 spilled at the default 128 cap).

#define B_ 8
#define S_ 8192
#define LDC 72     // chunk tile leading dim (shorts)
#define LDM 136    // M^T LDS leading dim (shorts)
#define LDQ 136    // q tile LDS leading dim (shorts)
#define BUFB 36864 // bytes per chunk double-buffer half (kt + vt)

using bf16x8 = __attribute__((ext_vector_type(8))) short;
using f32x16 = __attribute__((ext_vector_type(16))) float;

__device__ __forceinline__ short f2bf(float f) {
  union { float f; uint32_t u; } v; v.f = f;
  uint32_t r = v.u + 0x7fffu + ((v.u >> 16) & 1u);   // RNE
  return (short)(r >> 16);
}

__device__ __forceinline__ bf16x8 cvt8(float4 a, float4 b) {
  bf16x8 r;
  r[0] = f2bf(a.x); r[1] = f2bf(a.y); r[2] = f2bf(a.z); r[3] = f2bf(a.w);
  r[4] = f2bf(b.x); r[5] = f2bf(b.y); r[6] = f2bf(b.z); r[7] = f2bf(b.w);
  return r;
}

__global__ __launch_bounds__(512, 2) void fused_kernel(
    const float* __restrict__ x,
    const float* __restrict__ Wq, const float* __restrict__ bq,
    const float* __restrict__ Wk, const float* __restrict__ bk,
    const float* __restrict__ Wv, const float* __restrict__ bv,
    float* __restrict__ out)
{
  // [0,36864) buf0 | [36864,73728) buf1 | final: m_l=[0,34816), q_l=[36864,106496)
  __shared__ __align__(16) char smem[106496];

  const int tid  = threadIdx.x;
  const int lane = tid & 63;
  const int wv   = tid >> 6;        // 0..7
  const int c    = lane & 31;
  const int hl   = lane >> 5;

  // XCD swizzle: blk%8 = XCD -> batch b == XCD, so x[b] (4MB f32) fits that L2
  const int swz = (blockIdx.x & 7) * 32 + (blockIdx.x >> 3);
  const int b   = swz >> 5;
  const int n   = swz & 31;

  const int win_lo = (n == 0) ? 0 : n * 256 - 255;
  const int win_hi = (n == 31) ? S_ : n * 256 + 511;   // exclusive
  const int jlo    = (n == 0) ? 4 : 0;
  const int jhi    = (n == 31) ? 8 : 12;
  const int cbase  = n * 256 - 256;

  const float* xb = x + (size_t)b * S_ * 128;

  // ---- chunk-phase roles ----
  const bool is_k = (wv < 4);
  const int  pw   = wv & 3;
  const int  rt   = pw & 1;          // s row tile within chunk (32 rows)
  const int  ctp  = pw >> 1;         // col pair: d tiles {2ctp, 2ctp+1}
  const float* Wrole = is_k ? Wk : Wv;
  const float* brole = is_k ? bk : bv;

  // W B-frags in registers (persist through chunk loop): wfrag[t][kst] (64 v)
  bf16x8 wfrag[2][8];
  float  bias2[2];
  #pragma unroll
  for (int t = 0; t < 2; ++t) {
    const int ct = 2 * ctp + t;
    bias2[t] = brole[ct * 32 + c];
    const float* wr = Wrole + (size_t)(ct * 32 + c) * 128 + hl * 8;
    #pragma unroll
    for (int kst = 0; kst < 8; ++kst) {
      float4 f0 = *(const float4*)(wr + kst * 16);
      float4 f1 = *(const float4*)(wr + kst * 16 + 4);
      wfrag[t][kst] = cvt8(f0, f1);
    }
  }

  f32x16 macc[2];
  #pragma unroll
  for (int t = 0; t < 2; ++t)
    #pragma unroll
    for (int i = 0; i < 16; ++i) macc[t][i] = 0.f;

  // prologue: load + convert x A-frags for first chunk (32 v)
  bf16x8 af[8];
  {
    const float* xr = xb + (size_t)(cbase + jlo * 64 + rt * 32 + c) * 128 + hl * 8;
    #pragma unroll
    for (int kst = 0; kst < 8; ++kst) {
      float4 f0 = *(const float4*)(xr + kst * 16);
      float4 f1 = *(const float4*)(xr + kst * 16 + 4);
      af[kst] = cvt8(f0, f1);
    }
  }

  for (int j = jlo; j < jhi; ++j) {
    const int jj = j - jlo;
    short* ktc = (short*)(smem + (size_t)(jj & 1) * BUFB);
    short* vtc = ktc + 128 * LDC;
    const int c0 = cbase + j * 64;
    const bool more = (j + 1 < jhi);

    // prefetch next chunk's x rows into transient f32 (64 v, dies at cvt below)
    float4 f[16];
    if (more) {
      const float* xr = xb + (size_t)(c0 + 64 + rt * 32 + c) * 128 + hl * 8;
      #pragma unroll
      for (int kst = 0; kst < 8; ++kst) {
        f[2 * kst]     = *(const float4*)(xr + kst * 16);
        f[2 * kst + 1] = *(const float4*)(xr + kst * 16 + 4);
      }
    }

    // projection MFMA: C[s_local 32][d 64] for this wave's role
    f32x16 cacc[2];
    #pragma unroll
    for (int t = 0; t < 2; ++t)
      #pragma unroll
      for (int i = 0; i < 16; ++i) cacc[t][i] = bias2[t];
    #pragma unroll
    for (int kst = 0; kst < 8; ++kst)
      #pragma unroll
      for (int t = 0; t < 2; ++t)
        cacc[t] = __builtin_amdgcn_mfma_f32_32x32x16_bf16(af[kst], wfrag[t][kst], cacc[t], 0, 0, 0);

    // transposed LDS write [d][s], k edge-masked
    short* dst = is_k ? ktc : vtc;
    const bool maskme = is_k && ((c0 < win_lo) | (c0 + 64 > win_hi));
    #pragma unroll
    for (int t = 0; t < 2; ++t) {
      const int d = (2 * ctp + t) * 32 + c;
      #pragma unroll
      for (int g = 0; g < 4; ++g) {
        #pragma unroll
        for (int p = 0; p < 2; ++p) {
          const int reg = g * 4 + p * 2;
          const int sl  = rt * 32 + g * 8 + hl * 4 + p * 2;
          float v0 = cacc[t][reg], v1 = cacc[t][reg + 1];
          if (maskme) {
            const int sg = c0 + sl;
            if (sg < win_lo || sg >= win_hi) v0 = 0.f;
            if (sg + 1 < win_lo || sg + 1 >= win_hi) v1 = 0.f;
          }
          const uint32_t pk = (uint32_t)(uint16_t)f2bf(v0) |
                              ((uint32_t)(uint16_t)f2bf(v1) << 16);
          *(uint32_t*)(dst + d * LDC + sl) = pk;
        }
      }
    }

    // convert prefetched x in place (af's last use was the proj MFMAs above)
    if (more) {
      #pragma unroll
      for (int kst = 0; kst < 8; ++kst)
        af[kst] = cvt8(f[2 * kst], f[2 * kst + 1]);
    }
    __syncthreads();

    // M^T accumulate: wave (ht,dh) owns 32h x 64d
    {
      const int ht = wv >> 1, dh = wv & 1;
      #pragma unroll
      for (int kst = 0; kst < 4; ++kst) {
        bf16x8 a = *(const bf16x8*)(vtc + (ht * 32 + c) * LDC + kst * 16 + hl * 8);
        #pragma unroll
        for (int ntl = 0; ntl < 2; ++ntl) {
          bf16x8 bb = *(const bf16x8*)(ktc + ((dh * 2 + ntl) * 32 + c) * LDC + kst * 16 + hl * 8);
          macc[ntl] = __builtin_amdgcn_mfma_f32_32x32x16_bf16(a, bb, macc[ntl], 0, 0, 0);
        }
      }
    }
  }

  // ---------------- final phase (pressure-capped sequential staging) --------
  short* m_l = (short*)smem;                 // aliases buf0 (loop ends barriered)
  short* q_l = (short*)(smem + BUFB);

  const int rt2 = wv & 3;                    // q rows [64*rt2, +64)
  const int qcp = wv >> 2;                   // q col pair {2qcp, 2qcp+1}
  const int qs0 = n * 256;

  bf16x8 aq[2][8];
  // t=0 x rows: issue loads, slot m_l writes under the latency, then cvt
  {
    const float* xr = xb + (size_t)(qs0 + rt2 * 64 + c) * 128 + hl * 8;
    float4 f[16];
    #pragma unroll
    for (int kst = 0; kst < 8; ++kst) {
      f[2 * kst]     = *(const float4*)(xr + kst * 16);
      f[2 * kst + 1] = *(const float4*)(xr + kst * 16 + 4);
    }
    // write scaled M^T -> m_l (independent of the loads above)
    const float scale = 0.08838834764831845f;  // 1/sqrt(128)
    const int ht = wv >> 1, dh = wv & 1;
    #pragma unroll
    for (int ntl = 0; ntl < 2; ++ntl) {
      #pragma unroll
      for (int reg = 0; reg < 16; ++reg) {
        const int row = (reg & 3) + 8 * (reg >> 2) + 4 * hl;
        m_l[(ht * 32 + row) * LDM + (dh * 2 + ntl) * 32 + c] =
            f2bf(macc[ntl][reg] * scale);
      }
    }
    #pragma unroll
    for (int kst = 0; kst < 8; ++kst)
      aq[0][kst] = cvt8(f[2 * kst], f[2 * kst + 1]);
  }
  // t=1 x rows
  {
    const float* xr = xb + (size_t)(qs0 + rt2 * 64 + 32 + c) * 128 + hl * 8;
    float4 f[16];
    #pragma unroll
    for (int kst = 0; kst < 8; ++kst) {
      f[2 * kst]     = *(const float4*)(xr + kst * 16);
      f[2 * kst + 1] = *(const float4*)(xr + kst * 16 + 4);
    }
    #pragma unroll
    for (int kst = 0; kst < 8; ++kst)
      aq[1][kst] = cvt8(f[2 * kst], f[2 * kst + 1]);
  }
  // Wq, one col-tile at a time
  bf16x8 wq[2][8];
  float  qbias[2];
  #pragma unroll
  for (int t = 0; t < 2; ++t) {
    const int ct = 2 * qcp + t;
    qbias[t] = bq[ct * 32 + c];
    const float* wr = Wq + (size_t)(ct * 32 + c) * 128 + hl * 8;
    float4 f[16];
    #pragma unroll
    for (int kst = 0; kst < 8; ++kst) {
      f[2 * kst]     = *(const float4*)(wr + kst * 16);
      f[2 * kst + 1] = *(const float4*)(wr + kst * 16 + 4);
    }
    #pragma unroll
    for (int kst = 0; kst < 8; ++kst)
      wq[t][kst] = cvt8(f[2 * kst], f[2 * kst + 1]);
  }

  __syncthreads();   // B1: chunk-loop LDS fully released + m_l written

  // q projection: rows 64*rt2+32a, cols 32*(2qcp+t)
  f32x16 qacc[2][2];
  #pragma unroll
  for (int a = 0; a < 2; ++a)
    #pragma unroll
    for (int t = 0; t < 2; ++t)
      #pragma unroll
      for (int i = 0; i < 16; ++i) qacc[a][t][i] = qbias[t];
  #pragma unroll
  for (int kst = 0; kst < 8; ++kst)
    #pragma unroll
    for (int a = 0; a < 2; ++a)
      #pragma unroll
      for (int t = 0; t < 2; ++t)
        qacc[a][t] = __builtin_amdgcn_mfma_f32_32x32x16_bf16(aq[a][kst], wq[t][kst], qacc[a][t], 0, 0, 0);

  // q C-tiles -> q_l row-major [s_local][d]
  #pragma unroll
  for (int a = 0; a < 2; ++a) {
    #pragma unroll
    for (int t = 0; t < 2; ++t) {
      #pragma unroll
      for (int reg = 0; reg < 16; ++reg) {
        const int row = rt2 * 64 + a * 32 + (reg & 3) + 8 * (reg >> 2) + 4 * hl;
        q_l[row * LDQ + (2 * qcp + t) * 32 + c] = f2bf(qacc[a][t][reg]);
      }
    }
  }
  __syncthreads();   // B2

  // O = Q * M: wave owns q rows [32wv, +32)
  bf16x8 qf[8];
  {
    const short* qrow = q_l + (wv * 32 + c) * LDQ + hl * 8;
    #pragma unroll
    for (int kst = 0; kst < 8; ++kst) qf[kst] = *(const bf16x8*)(qrow + kst * 16);
  }
  f32x16 oacc[4];
  #pragma unroll
  for (int nt = 0; nt < 4; ++nt)
    #pragma unroll
    for (int i = 0; i < 16; ++i) oacc[nt][i] = 0.f;
  #pragma unroll
  for (int kst = 0; kst < 8; ++kst) {
    #pragma unroll
    for (int nt = 0; nt < 4; ++nt) {
      bf16x8 bb = *(const bf16x8*)(m_l + (nt * 32 + c) * LDM + kst * 16 + hl * 8);
      oacc[nt] = __builtin_amdgcn_mfma_f32_32x32x16_bf16(qf[kst], bb, oacc[nt], 0, 0, 0);
    }
  }
  __syncthreads();   // B3: all q_l reads done; patch region may be overwritten

  // epilogue: per-wave LDS patch (32x36 f32) -> coalesced float4 stores
  float* patch = (float*)(smem + BUFB) + wv * (32 * 36);
  float* outb  = out + ((size_t)b * S_ + n * 256 + wv * 32) * 128;
  #pragma unroll
  for (int nt = 0; nt < 4; ++nt) {
    #pragma unroll
    for (int reg = 0; reg < 16; ++reg) {
      const int row = (reg & 3) + 8 * (reg >> 2) + 4 * hl;
      patch[row * 36 + c] = oacc[nt][reg];
    }
    #pragma unroll
    for (int p = 0; p < 4; ++p) {
      const int row = p * 8 + (lane >> 3);
      float4 vv = *(const float4*)(patch + row * 36 + (lane & 7) * 4);
      *(float4*)(outb + (size_t)row * 128 + nt * 32 + (lane & 7) * 4) = vv;
    }
  }
}

// ---------------------------------------------------------------------------
extern "C" void kernel_launch(void* const* d_in, const int* in_sizes, int n_in,
                              void* d_out, int out_size, void* d_ws, size_t ws_size,
                              hipStream_t stream) {
  const float* x  = (const float*)d_in[0];
  const float* Wq = (const float*)d_in[1];
  const float* bq = (const float*)d_in[2];
  const float* Wk = (const float*)d_in[3];
  const float* bk = (const float*)d_in[4];
  const float* Wv = (const float*)d_in[5];
  const float* bv = (const float*)d_in[6];
  float* out = (float*)d_out;

  fused_kernel<<<256, 512, 0, stream>>>(x, Wq, bq, Wk, bk, Wv, bv, out);
}

// Round 6
// 135.212 us; speedup vs baseline: 1.6594x; 1.4150x over previous
//
#include <hip/hip_runtime.h>
#include <stdint.h>

// BlockAttention fused: B=8, S=8192, D=H=128, BLOCK=256, WINDOW=256 (halo 255)
// No softmax => out_blk = Q_blk @ (scale * K_win^T V_win).
// ONE kernel, 256 blocks (b,n) x 512 threads (8 waves), 1 block/CU.
// Register-light dataflow (r5 spilled): x chunks staged bf16 in LDS (double-
// buffered) so proj waves ds_read A-frags; W k/v B-frags in regs (64); final
// q-proj/O pipelined per 32-col tile through per-wave LDS transpose patches.

#define B_ 8
#define S_ 8192
#define LDC 72     // kt/vt chunk tile leading dim (shorts)
#define LDM 136    // M^T LDS leading dim (shorts)
#define LDX 136    // x chunk tile leading dim (shorts)
#define LDP 40     // per-wave q transpose patch leading dim (shorts)
#define BUFB 36864 // bytes per kt+vt double-buffer half
#define XOFF 73728 // x stage region offset
#define XBUF 17408 // bytes per x stage half (64*136*2)

using bf16x8 = __attribute__((ext_vector_type(8))) short;
using f32x16 = __attribute__((ext_vector_type(16))) float;

__device__ __forceinline__ short f2bf(float f) {
  union { float f; uint32_t u; } v; v.f = f;
  uint32_t r = v.u + 0x7fffu + ((v.u >> 16) & 1u);   // RNE
  return (short)(r >> 16);
}

__device__ __forceinline__ bf16x8 cvt8(float4 a, float4 b) {
  bf16x8 r;
  r[0] = f2bf(a.x); r[1] = f2bf(a.y); r[2] = f2bf(a.z); r[3] = f2bf(a.w);
  r[4] = f2bf(b.x); r[5] = f2bf(b.y); r[6] = f2bf(b.z); r[7] = f2bf(b.w);
  return r;
}

__global__ __launch_bounds__(512, 2) void fused_kernel(
    const float* __restrict__ x,
    const float* __restrict__ Wq, const float* __restrict__ bq,
    const float* __restrict__ Wk, const float* __restrict__ bk,
    const float* __restrict__ Wv, const float* __restrict__ bv,
    float* __restrict__ out)
{
  // [0,36864) buf0 kt|vt ; [36864,73728) buf1 ; [73728,108544) x0|x1
  // final: m_l=buf0[0,34816) ; qpat=buf1+wv*2560 ; opat=buf1+20480+wv*4608
  __shared__ __align__(16) char smem[108544];

  const int tid  = threadIdx.x;
  const int lane = tid & 63;
  const int wv   = tid >> 6;        // 0..7
  const int c    = lane & 31;
  const int hl   = lane >> 5;

  // XCD swizzle: blk%8 = XCD -> batch b == XCD, x[b] (4MB f32) fits that L2
  const int swz = (blockIdx.x & 7) * 32 + (blockIdx.x >> 3);
  const int b   = swz >> 5;
  const int n   = swz & 31;

  const int win_lo = (n == 0) ? 0 : n * 256 - 255;
  const int win_hi = (n == 31) ? S_ : n * 256 + 511;   // exclusive
  const int jlo    = (n == 0) ? 4 : 0;
  const int jhi    = (n == 31) ? 8 : 12;
  const int cbase  = n * 256 - 256;

  const float* xb = x + (size_t)b * S_ * 128;

  // chunk-phase roles
  const bool is_k = (wv < 4);
  const int  pw   = wv & 3;
  const int  rt   = pw & 1;          // s row tile within chunk (32 rows)
  const int  ctp  = pw >> 1;         // col pair: d tiles {2ctp, 2ctp+1}
  const float* Wrole = is_k ? Wk : Wv;
  const float* brole = is_k ? bk : bv;

  // x staging assignment: thread -> (row sr, col sc), 16 floats each
  const int sr = tid >> 3;           // 0..63
  const int sc = (tid & 7) << 4;     // 0,16,..,112

  // W B-frags in registers (64 VGPRs, persist through chunk loop)
  bf16x8 wfrag[2][8];
  float  bias2[2];
  #pragma unroll
  for (int t = 0; t < 2; ++t) {
    const int ct = 2 * ctp + t;
    bias2[t] = brole[ct * 32 + c];
    const float* wr = Wrole + (size_t)(ct * 32 + c) * 128 + hl * 8;
    #pragma unroll
    for (int kst = 0; kst < 8; ++kst) {
      float4 f0 = *(const float4*)(wr + kst * 16);
      float4 f1 = *(const float4*)(wr + kst * 16 + 4);
      wfrag[t][kst] = cvt8(f0, f1);
    }
  }

  f32x16 macc[2];
  #pragma unroll
  for (int t = 0; t < 2; ++t)
    #pragma unroll
    for (int i = 0; i < 16; ++i) macc[t][i] = 0.f;

  // prologue: stage first chunk's x -> x_l[0]
  {
    const float* xr = xb + (size_t)(cbase + jlo * 64 + sr) * 128 + sc;
    float4 f0 = ((const float4*)xr)[0], f1 = ((const float4*)xr)[1];
    float4 f2 = ((const float4*)xr)[2], f3 = ((const float4*)xr)[3];
    short* xl = (short*)(smem + XOFF);
    *(bf16x8*)(xl + sr * LDX + sc)     = cvt8(f0, f1);
    *(bf16x8*)(xl + sr * LDX + sc + 8) = cvt8(f2, f3);
  }
  __syncthreads();

  for (int j = jlo; j < jhi; ++j) {
    const int jj = j - jlo;
    const int jb = jj & 1;
    short* ktc = (short*)(smem + (size_t)jb * BUFB);
    short* vtc = ktc + 128 * LDC;
    const short* xcur = (const short*)(smem + XOFF + (size_t)jb * XBUF);
    const int c0 = cbase + j * 64;
    const bool more = (j + 1 < jhi);

    // issue next chunk's x loads early (16 transient VGPRs)
    float4 fx0, fx1, fx2, fx3;
    if (more) {
      const float* xr = xb + (size_t)(c0 + 64 + sr) * 128 + sc;
      fx0 = ((const float4*)xr)[0]; fx1 = ((const float4*)xr)[1];
      fx2 = ((const float4*)xr)[2]; fx3 = ((const float4*)xr)[3];
    }

    // projection MFMA: C[s_local 32][d 64], A-frags from LDS
    f32x16 cacc[2];
    #pragma unroll
    for (int t = 0; t < 2; ++t)
      #pragma unroll
      for (int i = 0; i < 16; ++i) cacc[t][i] = bias2[t];
    #pragma unroll
    for (int kst = 0; kst < 8; ++kst) {
      bf16x8 a = *(const bf16x8*)(xcur + (rt * 32 + c) * LDX + kst * 16 + hl * 8);
      cacc[0] = __builtin_amdgcn_mfma_f32_32x32x16_bf16(a, wfrag[0][kst], cacc[0], 0, 0, 0);
      cacc[1] = __builtin_amdgcn_mfma_f32_32x32x16_bf16(a, wfrag[1][kst], cacc[1], 0, 0, 0);
    }

    // transposed LDS write [d][s], k edge-masked
    short* dst = is_k ? ktc : vtc;
    const bool maskme = is_k && ((c0 < win_lo) | (c0 + 64 > win_hi));
    #pragma unroll
    for (int t = 0; t < 2; ++t) {
      const int d = (2 * ctp + t) * 32 + c;
      #pragma unroll
      for (int g = 0; g < 4; ++g) {
        #pragma unroll
        for (int p = 0; p < 2; ++p) {
          const int reg = g * 4 + p * 2;
          const int sl  = rt * 32 + g * 8 + hl * 4 + p * 2;
          float v0 = cacc[t][reg], v1 = cacc[t][reg + 1];
          if (maskme) {
            const int sg = c0 + sl;
            if (sg < win_lo || sg >= win_hi) v0 = 0.f;
            if (sg + 1 < win_lo || sg + 1 >= win_hi) v1 = 0.f;
          }
          const uint32_t pk = (uint32_t)(uint16_t)f2bf(v0) |
                              ((uint32_t)(uint16_t)f2bf(v1) << 16);
          *(uint32_t*)(dst + d * LDC + sl) = pk;
        }
      }
    }

    // stage next chunk's x into the other x buffer
    if (more) {
      short* xnx = (short*)(smem + XOFF + (size_t)(1 - jb) * XBUF);
      *(bf16x8*)(xnx + sr * LDX + sc)     = cvt8(fx0, fx1);
      *(bf16x8*)(xnx + sr * LDX + sc + 8) = cvt8(fx2, fx3);
    }
    __syncthreads();

    // M^T accumulate: wave (ht,dh) owns 32h x 64d
    {
      const int ht = wv >> 1, dh = wv & 1;
      #pragma unroll
      for (int kst = 0; kst < 4; ++kst) {
        bf16x8 a = *(const bf16x8*)(vtc + (ht * 32 + c) * LDC + kst * 16 + hl * 8);
        #pragma unroll
        for (int ntl = 0; ntl < 2; ++ntl) {
          bf16x8 bb = *(const bf16x8*)(ktc + ((dh * 2 + ntl) * 32 + c) * LDC + kst * 16 + hl * 8);
          macc[ntl] = __builtin_amdgcn_mfma_f32_32x32x16_bf16(a, bb, macc[ntl], 0, 0, 0);
        }
      }
    }
  }

  // ---------------- final phase ----------------
  short* m_l = (short*)smem;    // buf0; last Mbuild read buf1, so safe pre-B1

  // write scaled M^T -> m_l  (macc dead after this)
  const float scale = 0.08838834764831845f;  // 1/sqrt(128)
  {
    const int ht = wv >> 1, dh = wv & 1;
    #pragma unroll
    for (int ntl = 0; ntl < 2; ++ntl) {
      #pragma unroll
      for (int reg = 0; reg < 16; ++reg) {
        const int row = (reg & 3) + 8 * (reg >> 2) + 4 * hl;
        m_l[(ht * 32 + row) * LDM + (dh * 2 + ntl) * 32 + c] =
            f2bf(macc[ntl][reg] * scale);
      }
    }
  }

  // this wave's 32 q-rows: x A-frags (32 VGPRs), loads issued pre-barrier
  bf16x8 aq[8];
  {
    const float* xr = xb + (size_t)(n * 256 + wv * 32 + c) * 128 + hl * 8;
    #pragma unroll
    for (int kst = 0; kst < 8; ++kst) {
      float4 f0 = *(const float4*)(xr + kst * 16);
      float4 f1 = *(const float4*)(xr + kst * 16 + 4);
      aq[kst] = cvt8(f0, f1);
    }
  }

  __syncthreads();   // B1: m_l visible; chunk buffers released

  short* qpat = (short*)(smem + BUFB) + wv * (32 * LDP);          // wave-local
  float* opat = (float*)(smem + BUFB + 20480) + wv * (32 * 36);   // wave-local

  f32x16 oacc[4];
  #pragma unroll
  for (int ht = 0; ht < 4; ++ht)
    #pragma unroll
    for (int i = 0; i < 16; ++i) oacc[ht][i] = 0.f;

  // per d-tile pipeline: q-proj (8 MFMA) -> wave-local transpose -> O (8 MFMA)
  #pragma unroll
  for (int nt = 0; nt < 4; ++nt) {
    bf16x8 wqf[8];
    {
      const float* wr = Wq + (size_t)(nt * 32 + c) * 128 + hl * 8;
      #pragma unroll
      for (int kst = 0; kst < 8; ++kst) {
        float4 f0 = *(const float4*)(wr + kst * 16);
        float4 f1 = *(const float4*)(wr + kst * 16 + 4);
        wqf[kst] = cvt8(f0, f1);
      }
    }
    f32x16 qacc;
    {
      const float bb = bq[nt * 32 + c];
      #pragma unroll
      for (int i = 0; i < 16; ++i) qacc[i] = bb;
    }
    #pragma unroll
    for (int kst = 0; kst < 8; ++kst)
      qacc = __builtin_amdgcn_mfma_f32_32x32x16_bf16(aq[kst], wqf[kst], qacc, 0, 0, 0);

    // C-tile -> wave-local patch [qrow_local][d_local]
    #pragma unroll
    for (int reg = 0; reg < 16; ++reg) {
      const int row = (reg & 3) + 8 * (reg >> 2) + 4 * hl;
      qpat[row * LDP + c] = f2bf(qacc[reg]);
    }
    // A-frags back (same wave; lgkmcnt ordering suffices) + O MFMAs
    #pragma unroll
    for (int kst2 = 0; kst2 < 2; ++kst2) {
      bf16x8 qf = *(const bf16x8*)(qpat + c * LDP + kst2 * 16 + hl * 8);
      #pragma unroll
      for (int ht = 0; ht < 4; ++ht) {
        bf16x8 bb = *(const bf16x8*)(m_l + (ht * 32 + c) * LDM + nt * 32 + kst2 * 16 + hl * 8);
        oacc[ht] = __builtin_amdgcn_mfma_f32_32x32x16_bf16(qf, bb, oacc[ht], 0, 0, 0);
      }
    }
  }

  // epilogue: per-wave f32 patch -> coalesced float4 stores
  float* outb = out + ((size_t)b * S_ + n * 256 + wv * 32) * 128;
  #pragma unroll
  for (int ht = 0; ht < 4; ++ht) {
    #pragma unroll
    for (int reg = 0; reg < 16; ++reg) {
      const int row = (reg & 3) + 8 * (reg >> 2) + 4 * hl;
      opat[row * 36 + c] = oacc[ht][reg];
    }
    #pragma unroll
    for (int p = 0; p < 4; ++p) {
      const int row = p * 8 + (lane >> 3);
      float4 vv = *(const float4*)(opat + row * 36 + (lane & 7) * 4);
      *(float4*)(outb + (size_t)row * 128 + ht * 32 + (lane & 7) * 4) = vv;
    }
  }
}

// ---------------------------------------------------------------------------
extern "C" void kernel_launch(void* const* d_in, const int* in_sizes, int n_in,
                              void* d_out, int out_size, void* d_ws, size_t ws_size,
                              hipStream_t stream) {
  const float* x  = (const float*)d_in[0];
  const float* Wq = (const float*)d_in[1];
  const float* bq = (const float*)d_in[2];
  const float* Wk = (const float*)d_in[3];
  const float* bk = (const float*)d_in[4];
  const float* Wv = (const float*)d_in[5];
  const float* bv = (const float*)d_in[6];
  float* out = (float*)d_out;

  fused_kernel<<<256, 512, 0, stream>>>(x, Wq, bq, Wk, bk, Wv, bv, out);
}